// Round 6
// baseline (625.905 us; speedup 1.0000x reference)
//
#include <hip/hip_runtime.h>
#include <math.h>

#define Hh 128
#define Ww 128
#define HW (Hh*Ww)
#define Bn 4
#define Cn 64
#define On 64
#define CCH 4                 // channels per LDS chunk in dcn_k (double-buffered)
#define NCH (Cn/CCH)          // 16 chunks

// workspace layout (in floats)
#define OM_OFF   0                          // B*27*HW = 1,769,472 floats
#define CONV_OFF (Bn*27*HW)                 // B*64*HW = 4,194,304 floats
#define SS_OFF   (CONV_OFF + Bn*On*HW)      // 128 floats (scale[64], shift[64])
#define PART_OFF (SS_OFF + 128)             // 512 blocks * 128 floats partials

// ---------------------------------------------------------------------------
// Kernel A: offset-predicting 3x3 conv (C=64 -> 27), stride 1, pad 1.
// C split in 2 halves (grid.y) -> 1024 blocks (4/CU). Halves combine via
// atomicAdd into zero-initialized om. Bias folded into half 0. NO sigmoid
// here — dcn_k applies it when reading the mask (om holds raw values).
// ---------------------------------------------------------------------------
__global__ __launch_bounds__(128) void offset_conv_k(
    const float* __restrict__ x, const float* __restrict__ ow,
    const float* __restrict__ ob, float* __restrict__ om)
{
    int bh = blockIdx.x;
    int g  = blockIdx.y;            // 0..1: channels g*32 .. g*32+31
    int b = bh >> 7;
    int h = bh & 127;
    int w = threadIdx.x;

    float acc[27];
#pragma unroll
    for (int o = 0; o < 27; ++o) acc[o] = (g == 0) ? ob[o] : 0.0f;

    const float* xb = x + (size_t)b * Cn * HW;
    for (int c = g * 32; c < g * 32 + 32; ++c) {
        const float* xp = xb + c * HW;
        float v[9];
#pragma unroll
        for (int ky = 0; ky < 3; ++ky) {
            int yy = h + ky - 1;
            int yc = min(max(yy, 0), Hh - 1);
            bool vy = (yy >= 0) && (yy < Hh);
#pragma unroll
            for (int kx = 0; kx < 3; ++kx) {
                int xx = w + kx - 1;
                int xc = min(max(xx, 0), Ww - 1);
                bool vx = (xx >= 0) && (xx < Ww);
                v[ky * 3 + kx] = (vy && vx) ? xp[yc * Ww + xc] : 0.0f;
            }
        }
        const float* wp = ow + c * 9;   // ow[o*576 + c*9 + t]
#pragma unroll
        for (int o = 0; o < 27; ++o) {
            const float* wo = wp + o * 576;
#pragma unroll
            for (int t = 0; t < 9; ++t) acc[o] += v[t] * wo[t];
        }
    }

    int p = h * Ww + w;
#pragma unroll
    for (int o = 0; o < 27; ++o)
        atomicAdd(&om[((size_t)b * 27 + o) * HW + p], acc[o]);
}

// ---------------------------------------------------------------------------
// Kernel B: deformable sampling + DCN conv, LDS double-buffered pipeline.
// Block = 256 threads = one row (b,h), all 64 output channels.
// Per iteration: gather chunk cc+1 into registers sv (loads issue early),
// einsum chunk cc from LDS (hides gather vmcnt), ds_write sv -> other
// buffer, single barrier.
// CRITICAL #1: no __launch_bounds__ min-waves arg (R3: forced occupancy
//   spilled acc -> 4.9 GB scratch, 2.6x regression).
// CRITICAL #2: og readfirstlane'd so einsum weights scalarize to s_load
//   (R4: without it, 18k per-lane global loads, 438 us).
// ---------------------------------------------------------------------------
__global__ __launch_bounds__(256) void dcn_k(
    const float* __restrict__ x, const float* __restrict__ om,
    const float* __restrict__ dw, float* __restrict__ conv,
    float* __restrict__ part)
{
    int b = blockIdx.x >> 7;
    int h = blockIdx.x & 127;
    int t = threadIdx.x;

    __shared__ float sL[2][CCH * 9 * 128];   // 2 x 18 KB

    // ---- prologue: per-(k,px) corner indices & folded weights in registers
    int   pidx[5][4];
    float pfw[5][4];
#pragma unroll
    for (int i = 0; i < 5; ++i) {
        int pid = t + 256 * i;
        bool ok = (pid < 1152);           // only i==4, t>=128 is invalid
        int k  = pid >> 7;
        int px = pid & 127;
        if (ok) {
            int p = h * Ww + px;
            const float* omb = om + (size_t)b * 27 * HW;
            float ox = omb[(size_t)k * HW + p];
            float oy = omb[(size_t)(9 + k) * HW + p];
            float mr = omb[(size_t)(18 + k) * HW + p];
            float m  = 1.0f / (1.0f + __expf(-mr));     // sigmoid (om is raw)
            float py  = (float)(h - 1 + (k / 3)) + oy;
            float pxf = (float)(px - 1 + (k % 3)) + ox;
            float y0f = floorf(py), x0f = floorf(pxf);
            int y0 = (int)y0f, x0 = (int)x0f;
            float wy = py - y0f, wx = pxf - x0f;
#pragma unroll
            for (int dy = 0; dy < 2; ++dy) {
#pragma unroll
                for (int dx = 0; dx < 2; ++dx) {
                    int yi = y0 + dy, xi = x0 + dx;
                    bool valid = (yi >= 0) && (yi < Hh) && (xi >= 0) && (xi < Ww);
                    int yc = min(max(yi, 0), Hh - 1);
                    int xc = min(max(xi, 0), Ww - 1);
                    float wgt = (dy ? wy : 1.0f - wy) * (dx ? wx : 1.0f - wx);
                    pfw[i][dy * 2 + dx]  = valid ? (wgt * m) : 0.0f;
                    pidx[i][dy * 2 + dx] = yc * Ww + xc;
                }
            }
        } else {
#pragma unroll
            for (int j = 0; j < 4; ++j) { pfw[i][j] = 0.0f; pidx[i][j] = 0; }
        }
    }

    float acc[32];
#pragma unroll
    for (int j = 0; j < 32; ++j) acc[j] = 0.0f;

    int mypx = t & 127;
    int og_s = __builtin_amdgcn_readfirstlane(t >> 7);

    float sv[5][CCH];   // sampled values for the in-flight chunk

#define SAMPLE(cc_) do {                                                      \
    const float* xbase = x + (size_t)(b * Cn + (cc_) * CCH) * HW;             \
    _Pragma("unroll") for (int i = 0; i < 5; ++i) {                           \
        if (t + 256 * i < 1152) {                                             \
            _Pragma("unroll") for (int c2 = 0; c2 < CCH; ++c2) {              \
                const float* xc = xbase + c2 * HW;                            \
                sv[i][c2] = pfw[i][0] * xc[pidx[i][0]]                        \
                          + pfw[i][1] * xc[pidx[i][1]]                        \
                          + pfw[i][2] * xc[pidx[i][2]]                        \
                          + pfw[i][3] * xc[pidx[i][3]];                       \
            }                                                                 \
        }                                                                     \
    } } while (0)

#define WRITESV(nb_) do {                                                     \
    _Pragma("unroll") for (int i = 0; i < 5; ++i) {                           \
        int pid_ = t + 256 * i;                                               \
        if (pid_ < 1152) {                                                    \
            int k_ = pid_ >> 7, px_ = pid_ & 127;                             \
            _Pragma("unroll") for (int c2 = 0; c2 < CCH; ++c2)                \
                sL[nb_][(c2 * 9 + k_) * 128 + px_] = sv[i][c2];               \
        }                                                                     \
    } } while (0)

#define EINSUM(cb_, cc_) do {                                                 \
    const float* wchunk = dw + (size_t)(og_s * 32) * 576 + (cc_) * CCH * 9;   \
    _Pragma("unroll") for (int c2 = 0; c2 < CCH; ++c2) {                      \
        float s_[9];                                                          \
        _Pragma("unroll") for (int k_ = 0; k_ < 9; ++k_)                      \
            s_[k_] = sL[cb_][(c2 * 9 + k_) * 128 + mypx];                     \
        _Pragma("unroll") for (int j_ = 0; j_ < 32; ++j_) {                   \
            const float* wo = wchunk + (size_t)j_ * 576 + c2 * 9;             \
            _Pragma("unroll") for (int k_ = 0; k_ < 9; ++k_)                  \
                acc[j_] += s_[k_] * wo[k_];                                   \
        }                                                                     \
    } } while (0)

    SAMPLE(0);
    WRITESV(0);
    __syncthreads();

    for (int cc = 0; cc < NCH; ++cc) {
        int cb = cc & 1;
        if (cc + 1 < NCH) SAMPLE(cc + 1);   // loads issue early
        EINSUM(cb, cc);                     // hides gather latency
        if (cc + 1 < NCH) WRITESV(1 - cb);  // waits vmcnt only here
        __syncthreads();
    }

    // ---- store conv output (base derived from SGPR og_s)
    float* cv = conv + ((size_t)b * On + og_s * 32) * HW + h * Ww + mypx;
#pragma unroll
    for (int j = 0; j < 32; ++j) cv[(size_t)j * HW] = acc[j];

    // ---- block stats partials: wave shuffle-reduce, combine via LDS
    float* red = &sL[0][0];
#pragma unroll
    for (int j = 0; j < 32; ++j) {
        float s1 = acc[j];
        float s2 = acc[j] * acc[j];
#pragma unroll
        for (int off = 32; off > 0; off >>= 1) {
            s1 += __shfl_down(s1, off, 64);
            s2 += __shfl_down(s2, off, 64);
        }
        if ((t & 63) == 0) {
            int wv = t >> 6;                      // wave 0..3 ; og = wv>>1
            red[0 * 128 + wv * 32 + j] = s1;      // sums
            red[512 + wv * 32 + j]     = s2;      // sumsq (disjoint region)
        }
    }
    __syncthreads();
    if (t < 128) {
        int stat = t >> 6;         // 0=sum, 1=sumsq
        int o    = t & 63;
        int og2  = o >> 5, j = o & 31;
        float v = red[stat * 512 + (og2 * 2 + 0) * 32 + j]
                + red[stat * 512 + (og2 * 2 + 1) * 32 + j];
        part[(size_t)blockIdx.x * 128 + t] = v;
    }

#undef SAMPLE
#undef WRITESV
#undef EINSUM
}

// ---------------------------------------------------------------------------
// Kernel C: reduce per-block partials -> BN scale/shift. 1024 threads:
// 8-way row-parallel accumulate + LDS tree (R5's serial 512-loop was ~40us).
// ---------------------------------------------------------------------------
__global__ __launch_bounds__(1024) void stats_k(
    const float* __restrict__ part, const float* __restrict__ gamma,
    const float* __restrict__ beta, float* __restrict__ ss)
{
    int t = threadIdx.x;
    int col = t & 127, grp = t >> 7;          // 8 row-groups
    float a = 0.0f;
    for (int i = grp; i < Bn * Hh; i += 8) a += part[(size_t)i * 128 + col];
    __shared__ float red[1024];
    red[t] = a;
    __syncthreads();
    if (t < 128) {
        float v = 0.0f;
#pragma unroll
        for (int k = 0; k < 8; ++k) v += red[t + 128 * k];
        red[t] = v;
    }
    __syncthreads();
    if (t < 64) {
        float n = (float)(Bn * HW);
        float mu = red[t] / n;
        float var = red[64 + t] / n - mu * mu;
        float sc = gamma[t] * rsqrtf(var + 1e-5f);
        ss[t] = sc;
        ss[64 + t] = beta[t] - mu * sc;
    }
}

// ---------------------------------------------------------------------------
// Kernel D: apply BN + ReLU, vectorized float4
// ---------------------------------------------------------------------------
__global__ __launch_bounds__(256) void bnrelu_k(
    const float* __restrict__ conv, const float* __restrict__ ss,
    float* __restrict__ out)
{
    int i = blockIdx.x * blockDim.x + threadIdx.x;   // float4 index
    int ch = (i >> 12) & 63;                         // HW/4 = 4096 float4/plane
    float sc = ss[ch];
    float sh = ss[64 + ch];
    const float4* cv = (const float4*)conv;
    float4* ov = (float4*)out;
    float4 v = cv[i];
    v.x = fmaxf(v.x * sc + sh, 0.0f);
    v.y = fmaxf(v.y * sc + sh, 0.0f);
    v.z = fmaxf(v.z * sc + sh, 0.0f);
    v.w = fmaxf(v.w * sc + sh, 0.0f);
    ov[i] = v;
}

// ---------------------------------------------------------------------------
extern "C" void kernel_launch(void* const* d_in, const int* in_sizes, int n_in,
                              void* d_out, int out_size, void* d_ws, size_t ws_size,
                              hipStream_t stream)
{
    const float* x     = (const float*)d_in[0];
    const float* ow    = (const float*)d_in[1];
    const float* ob    = (const float*)d_in[2];
    const float* dw    = (const float*)d_in[3];
    // d_in[4] = dcn_b: cancels exactly under BN mean subtraction -> unused
    const float* gamma = (const float*)d_in[5];
    const float* beta  = (const float*)d_in[6];

    float* ws    = (float*)d_ws;
    float* om    = ws + OM_OFF;
    float* conv  = ws + CONV_OFF;
    float* ss    = ws + SS_OFF;
    float* part  = ws + PART_OFF;

    // om is accumulated into by 2 c-half blocks -> must start at zero
    hipMemsetAsync(om, 0, (size_t)Bn * 27 * HW * sizeof(float), stream);

    offset_conv_k<<<dim3(Bn * Hh, 2), dim3(128), 0, stream>>>(x, ow, ob, om);
    dcn_k<<<dim3(Bn * Hh), dim3(256), 0, stream>>>(x, om, dw, conv, part);
    stats_k<<<dim3(1), dim3(1024), 0, stream>>>(part, gamma, beta, ss);
    bnrelu_k<<<dim3(Bn * On * HW / 4 / 256), dim3(256), 0, stream>>>(conv, ss, (float*)d_out);
}

// Round 7
// 350.404 us; speedup vs baseline: 1.7862x; 1.7862x over previous
//
#include <hip/hip_runtime.h>
#include <math.h>

#define Hh 128
#define Ww 128
#define HW (Hh*Ww)
#define Bn 4
#define Cn 64
#define On 64
#define CCH 8                 // channels per LDS chunk in dcn_k
#define NCH (Cn/CCH)          // 8 chunks

// workspace layout (in floats)
#define OM_OFF   0                          // B*27*HW = 1,769,472 floats
#define CONV_OFF (Bn*27*HW)                 // B*64*HW = 4,194,304 floats
#define SS_OFF   (CONV_OFF + Bn*On*HW)      // 128 floats (scale[64], shift[64])
#define PART_OFF (SS_OFF + 128)             // 1024 blocks * 128 floats partials

// ---------------------------------------------------------------------------
// Kernel A: offset-predicting 3x3 conv (C=64 -> 27), stride 1, pad 1.
// C split in 2 halves (grid.y) -> 1024 blocks. Halves combine via atomicAdd
// into zero-initialized om. Bias folded into half 0. Sigmoid applied by
// dcn_k's prologue (om holds raw values).
// ---------------------------------------------------------------------------
__global__ __launch_bounds__(128) void offset_conv_k(
    const float* __restrict__ x, const float* __restrict__ ow,
    const float* __restrict__ ob, float* __restrict__ om)
{
    int bh = blockIdx.x;
    int g  = blockIdx.y;            // 0..1: channels g*32 .. g*32+31
    int b = bh >> 7;
    int h = bh & 127;
    int w = threadIdx.x;

    float acc[27];
#pragma unroll
    for (int o = 0; o < 27; ++o) acc[o] = (g == 0) ? ob[o] : 0.0f;

    const float* xb = x + (size_t)b * Cn * HW;
    for (int c = g * 32; c < g * 32 + 32; ++c) {
        const float* xp = xb + c * HW;
        float v[9];
#pragma unroll
        for (int ky = 0; ky < 3; ++ky) {
            int yy = h + ky - 1;
            int yc = min(max(yy, 0), Hh - 1);
            bool vy = (yy >= 0) && (yy < Hh);
#pragma unroll
            for (int kx = 0; kx < 3; ++kx) {
                int xx = w + kx - 1;
                int xc = min(max(xx, 0), Ww - 1);
                bool vx = (xx >= 0) && (xx < Ww);
                v[ky * 3 + kx] = (vy && vx) ? xp[yc * Ww + xc] : 0.0f;
            }
        }
        const float* wp = ow + c * 9;   // ow[o*576 + c*9 + t]
#pragma unroll
        for (int o = 0; o < 27; ++o) {
            const float* wo = wp + o * 576;
#pragma unroll
            for (int t = 0; t < 9; ++t) acc[o] += v[t] * wo[t];
        }
    }

    int p = h * Ww + w;
#pragma unroll
    for (int o = 0; o < 27; ++o)
        atomicAdd(&om[((size_t)b * 27 + o) * HW + p], acc[o]);
}

// ---------------------------------------------------------------------------
// Kernel B: deformable sampling + DCN conv, LDS-staged, HALF-ROW blocks.
// Block = 256 threads = 64 pixels x 4 output-groups (16 outputs each).
// Grid = 1024 (b x h x half) -> 4 blocks/CU, 16 waves/CU: cross-block
// wave overlap hides the sample->einsum barriers (R6's intra-block
// pipeline at 2 blocks/CU regressed; occupancy is the real lever).
// CRITICAL #1: no __launch_bounds__ min-waves arg (R3: forced occupancy
//   spilled acc -> 4.9 GB scratch, 2.6x regression).
// CRITICAL #2: og readfirstlane'd so einsum weights scalarize to s_load
//   (R4: without it, 18k per-lane global loads, 438 us).
// ---------------------------------------------------------------------------
__global__ __launch_bounds__(256) void dcn_k(
    const float* __restrict__ x, const float* __restrict__ om,
    const float* __restrict__ dw, float* __restrict__ conv,
    float* __restrict__ part)
{
    int blk  = blockIdx.x;          // b(4) x h(128) x half(2)
    int half = blk & 1;
    int h    = (blk >> 1) & 127;
    int b    = blk >> 8;
    int px0  = half * 64;
    int t    = threadIdx.x;

    __shared__ float sL[CCH * 9 * 64];   // 18 KB

    // ---- prologue: units = k(9) x px(64) = 576; thread owns t, t+256, t+512
    int   pidx[3][4];
    float pfw[3][4];
#pragma unroll
    for (int i = 0; i < 3; ++i) {
        int pid = t + 256 * i;
        bool ok = (pid < 576);
        int k  = pid >> 6;
        int px = pid & 63;
        if (ok) {
            int p = h * Ww + px0 + px;
            const float* omb = om + (size_t)b * 27 * HW;
            float ox = omb[(size_t)k * HW + p];
            float oy = omb[(size_t)(9 + k) * HW + p];
            float mr = omb[(size_t)(18 + k) * HW + p];
            float m  = 1.0f / (1.0f + __expf(-mr));     // sigmoid (om is raw)
            float py  = (float)(h - 1 + (k / 3)) + oy;
            float pxf = (float)(px0 + px - 1 + (k % 3)) + ox;
            float y0f = floorf(py), x0f = floorf(pxf);
            int y0 = (int)y0f, x0 = (int)x0f;
            float wy = py - y0f, wx = pxf - x0f;
#pragma unroll
            for (int dy = 0; dy < 2; ++dy) {
#pragma unroll
                for (int dx = 0; dx < 2; ++dx) {
                    int yi = y0 + dy, xi = x0 + dx;
                    bool valid = (yi >= 0) && (yi < Hh) && (xi >= 0) && (xi < Ww);
                    int yc = min(max(yi, 0), Hh - 1);
                    int xc = min(max(xi, 0), Ww - 1);
                    float wgt = (dy ? wy : 1.0f - wy) * (dx ? wx : 1.0f - wx);
                    pfw[i][dy * 2 + dx]  = valid ? (wgt * m) : 0.0f;
                    pidx[i][dy * 2 + dx] = yc * Ww + xc;
                }
            }
        } else {
#pragma unroll
            for (int j = 0; j < 4; ++j) { pfw[i][j] = 0.0f; pidx[i][j] = 0; }
        }
    }

    float acc[16];
#pragma unroll
    for (int j = 0; j < 16; ++j) acc[j] = 0.0f;

    int mypx = t & 63;
    // wave index == output group; readfirstlane -> SGPR -> s_load weights
    int og_s = __builtin_amdgcn_readfirstlane(t >> 6);

    for (int cc = 0; cc < NCH; ++cc) {
        // ---- sampling phase: fill sL for channels cc*8 .. cc*8+7
        const float* xbase = x + (size_t)(b * Cn + cc * CCH) * HW;
#pragma unroll
        for (int i = 0; i < 3; ++i) {
            int pid = t + 256 * i;
            if (pid < 576) {
                int k  = pid >> 6;
                int px = pid & 63;
#pragma unroll
                for (int c2 = 0; c2 < CCH; ++c2) {
                    const float* xc = xbase + c2 * HW;
                    float v = pfw[i][0] * xc[pidx[i][0]]
                            + pfw[i][1] * xc[pidx[i][1]]
                            + pfw[i][2] * xc[pidx[i][2]]
                            + pfw[i][3] * xc[pidx[i][3]];
                    sL[(c2 * 9 + k) * 64 + px] = v;
                }
            }
        }
        __syncthreads();

        // ---- einsum phase: acc[j] += sL . w   (weights via s_load)
        const float* wchunk = dw + (size_t)(og_s * 16) * 576 + cc * CCH * 9;
        for (int c2 = 0; c2 < CCH; ++c2) {
            float s[9];
#pragma unroll
            for (int k = 0; k < 9; ++k) s[k] = sL[(c2 * 9 + k) * 64 + mypx];
#pragma unroll
            for (int j = 0; j < 16; ++j) {
                const float* wo = wchunk + (size_t)j * 576 + c2 * 9;
#pragma unroll
                for (int k = 0; k < 9; ++k) acc[j] += s[k] * wo[k];
            }
        }
        __syncthreads();   // WAR: next chunk overwrites sL
    }

    // ---- store conv output (base derived from SGPR og_s)
    float* cv = conv + ((size_t)b * On + og_s * 16) * HW + h * Ww + px0 + mypx;
#pragma unroll
    for (int j = 0; j < 16; ++j) cv[(size_t)j * HW] = acc[j];

    // ---- stats partials: each wave owns 16 distinct channels -> wave
    // shuffle-reduce over its 64 pixels, lane 0 writes directly to part
#pragma unroll
    for (int j = 0; j < 16; ++j) {
        float s1 = acc[j];
        float s2 = acc[j] * acc[j];
#pragma unroll
        for (int off = 32; off > 0; off >>= 1) {
            s1 += __shfl_down(s1, off, 64);
            s2 += __shfl_down(s2, off, 64);
        }
        if ((t & 63) == 0) {
            part[(size_t)blk * 128 + og_s * 16 + j]      = s1;
            part[(size_t)blk * 128 + 64 + og_s * 16 + j] = s2;
        }
    }
}

// ---------------------------------------------------------------------------
// Kernel C: reduce per-block partials (1024 rows) -> BN scale/shift.
// 1024 threads: 8-way row-parallel accumulate + LDS tree.
// ---------------------------------------------------------------------------
__global__ __launch_bounds__(1024) void stats_k(
    const float* __restrict__ part, const float* __restrict__ gamma,
    const float* __restrict__ beta, float* __restrict__ ss)
{
    int t = threadIdx.x;
    int col = t & 127, grp = t >> 7;          // 8 row-groups
    float a = 0.0f;
    for (int i = grp; i < Bn * Hh * 2; i += 8) a += part[(size_t)i * 128 + col];
    __shared__ float red[1024];
    red[t] = a;
    __syncthreads();
    if (t < 128) {
        float v = 0.0f;
#pragma unroll
        for (int k = 0; k < 8; ++k) v += red[t + 128 * k];
        red[t] = v;
    }
    __syncthreads();
    if (t < 64) {
        float n = (float)(Bn * HW);
        float mu = red[t] / n;
        float var = red[64 + t] / n - mu * mu;
        float sc = gamma[t] * rsqrtf(var + 1e-5f);
        ss[t] = sc;
        ss[64 + t] = beta[t] - mu * sc;
    }
}

// ---------------------------------------------------------------------------
// Kernel D: apply BN + ReLU, vectorized float4
// ---------------------------------------------------------------------------
__global__ __launch_bounds__(256) void bnrelu_k(
    const float* __restrict__ conv, const float* __restrict__ ss,
    float* __restrict__ out)
{
    int i = blockIdx.x * blockDim.x + threadIdx.x;   // float4 index
    int ch = (i >> 12) & 63;                         // HW/4 = 4096 float4/plane
    float sc = ss[ch];
    float sh = ss[64 + ch];
    const float4* cv = (const float4*)conv;
    float4* ov = (float4*)out;
    float4 v = cv[i];
    v.x = fmaxf(v.x * sc + sh, 0.0f);
    v.y = fmaxf(v.y * sc + sh, 0.0f);
    v.z = fmaxf(v.z * sc + sh, 0.0f);
    v.w = fmaxf(v.w * sc + sh, 0.0f);
    ov[i] = v;
}

// ---------------------------------------------------------------------------
extern "C" void kernel_launch(void* const* d_in, const int* in_sizes, int n_in,
                              void* d_out, int out_size, void* d_ws, size_t ws_size,
                              hipStream_t stream)
{
    const float* x     = (const float*)d_in[0];
    const float* ow    = (const float*)d_in[1];
    const float* ob    = (const float*)d_in[2];
    const float* dw    = (const float*)d_in[3];
    // d_in[4] = dcn_b: cancels exactly under BN mean subtraction -> unused
    const float* gamma = (const float*)d_in[5];
    const float* beta  = (const float*)d_in[6];

    float* ws    = (float*)d_ws;
    float* om    = ws + OM_OFF;
    float* conv  = ws + CONV_OFF;
    float* ss    = ws + SS_OFF;
    float* part  = ws + PART_OFF;

    // om is accumulated into by 2 c-half blocks -> must start at zero
    hipMemsetAsync(om, 0, (size_t)Bn * 27 * HW * sizeof(float), stream);

    offset_conv_k<<<dim3(Bn * Hh, 2), dim3(128), 0, stream>>>(x, ow, ob, om);
    dcn_k<<<dim3(Bn * Hh * 2), dim3(256), 0, stream>>>(x, om, dw, conv, part);
    stats_k<<<dim3(1), dim3(1024), 0, stream>>>(part, gamma, beta, ss);
    bnrelu_k<<<dim3(Bn * On * HW / 4 / 256), dim3(256), 0, stream>>>(conv, ss, (float*)d_out);
}

// Round 8
// 277.492 us; speedup vs baseline: 2.2556x; 1.2628x over previous
//
#include <hip/hip_runtime.h>
#include <math.h>

#define Hh 128
#define Ww 128
#define HW (Hh*Ww)
#define Bn 4
#define Cn 64
#define On 64

#define KP 296                 // padded K stride (shorts) for A-LDS (288+8)
#define OMP 66                 // padded px stride for om LDS

typedef __attribute__((ext_vector_type(8))) short bf16x8;
typedef __attribute__((ext_vector_type(4))) float f32x4;

// fp32 -> bf16 with round-to-nearest-even
static __device__ __forceinline__ short f2bf(float f) {
    unsigned u = __builtin_bit_cast(unsigned, f);
    u += 0x7FFFu + ((u >> 16) & 1u);
    return (short)(u >> 16);
}

// workspace layout (in floats)
#define CONV_OFF 0                          // B*64*HW = 4,194,304 floats
#define PART_OFF (Bn*On*HW)                 // 1024 blocks * 128 floats
#define SS_OFF   (PART_OFF + 1024*128)      // 128 floats (scale, shift)

// ---------------------------------------------------------------------------
// Fused kernel: offset-conv (MFMA) -> bilinear prep -> deformable sampling
// -> DCN conv (MFMA) -> conv store + BN stats partials.
// Block = 256 threads = half-row (64 px), grid = B*H*2 = 1024.
// Offsets at pixel p depend only on x's 3x3 nbhd; dcn at p reads offsets
// only at p -> block-local fusion is exact (no om workspace / atomics).
// CRITICAL #1: no __launch_bounds__ min-waves arg (R3: forced occupancy
//   spilled acc -> 4.9 GB scratch, 2.6x regression).
// CRITICAL #2: wave id readfirstlane'd (R4: divergent-looking uniform index
//   turned weight reads into per-lane loads).
// MFMA 16x16x32 bf16 layouts (guide-verified):
//   A: lane holds A[m=lane&15][k=(lane>>4)*8+j]   (ds_read_b128 from [px][k])
//   B: lane holds B[k=(lane>>4)*8+j][n=lane&15]   (per-lane global, fp32->bf16)
//   D: lane holds D[row=(lane>>4)*4+r][col=lane&15]
// ---------------------------------------------------------------------------
__global__ __launch_bounds__(256) void dcn_fused_k(
    const float* __restrict__ x,  const float* __restrict__ ow,
    const float* __restrict__ ob, const float* __restrict__ dw,
    float* __restrict__ conv,     float* __restrict__ part)
{
    int blk  = blockIdx.x;          // b(2b) | h(7b) | half(1b)
    int half = blk & 1;
    int h    = (blk >> 1) & 127;
    int b    = blk >> 8;
    int px0  = half * 64;
    int t    = threadIdx.x;
    int lane = t & 63;
    int quad = lane >> 4;
    int l15  = lane & 15;
    int w_s  = __builtin_amdgcn_readfirstlane(t >> 6);   // wave 0..3 (SGPR)

    __shared__ short sA[64 * KP];       // 37,888 B : A-operand (bf16) [px][k]
    __shared__ float sOM[27 * OMP];     //  7,128 B : offset-conv out [o][px]

    // ---- fill-unit ownership: 576 units = k(9) x px(64); thread owns <=3
    int ukk[3], upx[3]; bool uok[3];
#pragma unroll
    for (int i = 0; i < 3; ++i) {
        int pid = t + 256 * i;
        uok[i] = (pid < 576);
        ukk[i] = pid >> 6;
        upx[i] = pid & 63;
    }

    // ================= Phase 1: offset conv via MFMA =================
    // M=64 px, N=32 (27 real), K=576 in 2 chunks of 288 (9 ksteps)
    int nt_o = w_s & 1;                 // wave -> (ntile, m-half)
    int mh   = w_s >> 1;
    int o_ow = nt_o * 16 + l15;         // my output column (0..31)
    f32x4 oacc[2] = {{0,0,0,0},{0,0,0,0}};

    for (int ch = 0; ch < 2; ++ch) {
        int cbase = ch * 32;
        // ---- im2col fill (zero-padded 3x3 taps), bf16 into sA[px][k]
#pragma unroll
        for (int i = 0; i < 3; ++i) {
            if (uok[i]) {
                int kk = ukk[i], px = upx[i];
                int yy = h + kk / 3 - 1;
                int xx = px0 + px + kk % 3 - 1;
                bool valid = ((unsigned)yy < (unsigned)Hh) && ((unsigned)xx < (unsigned)Ww);
                const float* xp = x + ((size_t)b * Cn + cbase) * HW + yy * Ww + xx;
                short* dst = &sA[px * KP + cbase ? 0 : 0]; (void)dst;
#pragma unroll
                for (int c2 = 0; c2 < 32; ++c2) {
                    float v = valid ? xp[(size_t)c2 * HW] : 0.0f;
                    sA[px * KP + c2 * 9 + kk] = f2bf(v);
                }
            }
        }
        __syncthreads();

        // ---- B-frags from ow (o rows >=27 are zero)
        bf16x8 bfr[9];
#pragma unroll
        for (int ks = 0; ks < 9; ++ks) {
            if (o_ow < 27) {
                const f32x4* wv = (const f32x4*)(ow + (size_t)o_ow * 576 + ch * 288 + ks * 32 + quad * 8);
                f32x4 w0 = wv[0], w1 = wv[1];
                bf16x8 f;
                f[0]=f2bf(w0[0]); f[1]=f2bf(w0[1]); f[2]=f2bf(w0[2]); f[3]=f2bf(w0[3]);
                f[4]=f2bf(w1[0]); f[5]=f2bf(w1[1]); f[6]=f2bf(w1[2]); f[7]=f2bf(w1[3]);
                bfr[ks] = f;
            } else {
                bf16x8 z; 
#pragma unroll
                for (int j = 0; j < 8; ++j) z[j] = 0;
                bfr[ks] = z;
            }
        }
        // ---- GEMM: my 2 M-tiles (px mh*32 .. mh*32+31)
#pragma unroll
        for (int ks = 0; ks < 9; ++ks) {
#pragma unroll
            for (int m2 = 0; m2 < 2; ++m2) {
                int mt = mh * 2 + m2;
                bf16x8 a = *(const bf16x8*)&sA[(mt * 16 + l15) * KP + ks * 32 + quad * 8];
                oacc[m2] = __builtin_amdgcn_mfma_f32_16x16x32_bf16(a, bfr[ks], oacc[m2], 0, 0, 0);
            }
        }
        __syncthreads();     // before next chunk overwrites sA
    }
    // ---- D -> sOM (+bias). lane covers o=o_ow, px = mt*16 + quad*4 + r
    if (o_ow < 27) {
        float bias = ob[o_ow];
#pragma unroll
        for (int m2 = 0; m2 < 2; ++m2) {
            int pxb = (mh * 2 + m2) * 16 + quad * 4;
#pragma unroll
            for (int r = 0; r < 4; ++r)
                sOM[o_ow * OMP + pxb + r] = oacc[m2][r] + bias;
        }
    }
    __syncthreads();

    // ================= Phase 2: bilinear prep (per fill-unit) ============
    int   pidx[3][4];
    float pfw[3][4];
#pragma unroll
    for (int i = 0; i < 3; ++i) {
        if (uok[i]) {
            int k = ukk[i], px = upx[i];
            float ox = sOM[k * OMP + px];
            float oy = sOM[(9 + k) * OMP + px];
            float mr = sOM[(18 + k) * OMP + px];
            float m  = 1.0f / (1.0f + __expf(-mr));     // sigmoid
            float py  = (float)(h - 1 + (k / 3)) + oy;
            float pxf = (float)(px0 + px - 1 + (k % 3)) + ox;
            float y0f = floorf(py), x0f = floorf(pxf);
            int y0 = (int)y0f, x0 = (int)x0f;
            float wy = py - y0f, wx = pxf - x0f;
#pragma unroll
            for (int dy = 0; dy < 2; ++dy) {
#pragma unroll
                for (int dx = 0; dx < 2; ++dx) {
                    int yi = y0 + dy, xi = x0 + dx;
                    bool valid = (yi >= 0) && (yi < Hh) && (xi >= 0) && (xi < Ww);
                    int yc = min(max(yi, 0), Hh - 1);
                    int xc = min(max(xi, 0), Ww - 1);
                    float wgt = (dy ? wy : 1.0f - wy) * (dx ? wx : 1.0f - wx);
                    pfw[i][dy * 2 + dx]  = valid ? (wgt * m) : 0.0f;
                    pidx[i][dy * 2 + dx] = yc * Ww + xc;
                }
            }
        } else {
#pragma unroll
            for (int j = 0; j < 4; ++j) { pfw[i][j] = 0.0f; pidx[i][j] = 0; }
        }
    }

    // ================= Phase 3: sampling + DCN GEMM ======================
    // wave owns N-tile = outputs w_s*16 .. w_s*16+15; iterates 4 M-tiles
    int o_dw = w_s * 16 + l15;
    f32x4 acc[4] = {{0,0,0,0},{0,0,0,0},{0,0,0,0},{0,0,0,0}};

    for (int ch = 0; ch < 2; ++ch) {
        int cbase = ch * 32;
        // ---- deformable sample fill, bf16 into sA[px][k]
#pragma unroll
        for (int i = 0; i < 3; ++i) {
            if (uok[i]) {
                int kk = ukk[i], px = upx[i];
                const float* xb = x + ((size_t)b * Cn + cbase) * HW;
#pragma unroll
                for (int c2 = 0; c2 < 32; ++c2) {
                    const float* xc = xb + (size_t)c2 * HW;
                    float v = pfw[i][0] * xc[pidx[i][0]]
                            + pfw[i][1] * xc[pidx[i][1]]
                            + pfw[i][2] * xc[pidx[i][2]]
                            + pfw[i][3] * xc[pidx[i][3]];
                    sA[px * KP + c2 * 9 + kk] = f2bf(v);
                }
            }
        }
        __syncthreads();

        // ---- B-frags from dw for my 16 outputs
        bf16x8 bfr[9];
#pragma unroll
        for (int ks = 0; ks < 9; ++ks) {
            const f32x4* wv = (const f32x4*)(dw + (size_t)o_dw * 576 + ch * 288 + ks * 32 + quad * 8);
            f32x4 w0 = wv[0], w1 = wv[1];
            bf16x8 f;
            f[0]=f2bf(w0[0]); f[1]=f2bf(w0[1]); f[2]=f2bf(w0[2]); f[3]=f2bf(w0[3]);
            f[4]=f2bf(w1[0]); f[5]=f2bf(w1[1]); f[6]=f2bf(w1[2]); f[7]=f2bf(w1[3]);
            bfr[ks] = f;
        }
#pragma unroll
        for (int ks = 0; ks < 9; ++ks) {
#pragma unroll
            for (int mt = 0; mt < 4; ++mt) {
                bf16x8 a = *(const bf16x8*)&sA[(mt * 16 + l15) * KP + ks * 32 + quad * 8];
                acc[mt] = __builtin_amdgcn_mfma_f32_16x16x32_bf16(a, bfr[ks], acc[mt], 0, 0, 0);
            }
        }
        __syncthreads();
    }

    // ================= Phase 4: store conv + stats partials ==============
    // lane holds o=o_dw, px = mt*16 + quad*4 + r (4 consecutive px / tile)
#pragma unroll
    for (int mt = 0; mt < 4; ++mt) {
        size_t idx = ((size_t)b * On + o_dw) * HW + h * Ww + px0 + mt * 16 + quad * 4;
        *(f32x4*)(conv + idx) = acc[mt];
    }
    float s1 = 0.0f, s2 = 0.0f;
#pragma unroll
    for (int mt = 0; mt < 4; ++mt) {
#pragma unroll
        for (int r = 0; r < 4; ++r) {
            float v = acc[mt][r];
            s1 += v;
            s2 += v * v;
        }
    }
    // lanes L, L+16, L+32, L+48 share the same o -> fold
    s1 += __shfl_down(s1, 32, 64);  s2 += __shfl_down(s2, 32, 64);
    s1 += __shfl_down(s1, 16, 64);  s2 += __shfl_down(s2, 16, 64);
    if (lane < 16) {
        part[(size_t)blk * 128 + o_dw]      = s1;
        part[(size_t)blk * 128 + 64 + o_dw] = s2;
    }
}

// ---------------------------------------------------------------------------
// Kernel C: reduce per-block partials (1024 rows) -> BN scale/shift.
// ---------------------------------------------------------------------------
__global__ __launch_bounds__(1024) void stats_k(
    const float* __restrict__ part, const float* __restrict__ gamma,
    const float* __restrict__ beta, float* __restrict__ ss)
{
    int t = threadIdx.x;
    int col = t & 127, grp = t >> 7;          // 8 row-groups
    float a = 0.0f;
    for (int i = grp; i < Bn * Hh * 2; i += 8) a += part[(size_t)i * 128 + col];
    __shared__ float red[1024];
    red[t] = a;
    __syncthreads();
    if (t < 128) {
        float v = 0.0f;
#pragma unroll
        for (int k = 0; k < 8; ++k) v += red[t + 128 * k];
        red[t] = v;
    }
    __syncthreads();
    if (t < 64) {
        float n = (float)(Bn * HW);
        float mu = red[t] / n;
        float var = red[64 + t] / n - mu * mu;
        float sc = gamma[t] * rsqrtf(var + 1e-5f);
        ss[t] = sc;
        ss[64 + t] = beta[t] - mu * sc;
    }
}

// ---------------------------------------------------------------------------
// Kernel D: apply BN + ReLU, vectorized float4
// ---------------------------------------------------------------------------
__global__ __launch_bounds__(256) void bnrelu_k(
    const float* __restrict__ conv, const float* __restrict__ ss,
    float* __restrict__ out)
{
    int i = blockIdx.x * blockDim.x + threadIdx.x;   // float4 index
    int ch = (i >> 12) & 63;                         // HW/4 = 4096 float4/plane
    float sc = ss[ch];
    float sh = ss[64 + ch];
    const float4* cv = (const float4*)conv;
    float4* ov = (float4*)out;
    float4 v = cv[i];
    v.x = fmaxf(v.x * sc + sh, 0.0f);
    v.y = fmaxf(v.y * sc + sh, 0.0f);
    v.z = fmaxf(v.z * sc + sh, 0.0f);
    v.w = fmaxf(v.w * sc + sh, 0.0f);
    ov[i] = v;
}

// ---------------------------------------------------------------------------
extern "C" void kernel_launch(void* const* d_in, const int* in_sizes, int n_in,
                              void* d_out, int out_size, void* d_ws, size_t ws_size,
                              hipStream_t stream)
{
    const float* x     = (const float*)d_in[0];
    const float* ow    = (const float*)d_in[1];
    const float* ob    = (const float*)d_in[2];
    const float* dw    = (const float*)d_in[3];
    // d_in[4] = dcn_b: cancels exactly under BN mean subtraction -> unused
    const float* gamma = (const float*)d_in[5];
    const float* beta  = (const float*)d_in[6];

    float* ws   = (float*)d_ws;
    float* conv = ws + CONV_OFF;
    float* part = ws + PART_OFF;
    float* ss   = ws + SS_OFF;

    dcn_fused_k<<<dim3(Bn * Hh * 2), dim3(256), 0, stream>>>(x, ow, ob, dw, conv, part);
    stats_k<<<dim3(1), dim3(1024), 0, stream>>>(part, gamma, beta, ss);
    bnrelu_k<<<dim3(Bn * On * HW / 4 / 256), dim3(256), 0, stream>>>(conv, ss, (float*)d_out);
}

// Round 9
// 236.395 us; speedup vs baseline: 2.6477x; 1.1738x over previous
//
#include <hip/hip_runtime.h>
#include <math.h>

#define Hh 128
#define Ww 128
#define HW (Hh*Ww)
#define Bn 4
#define Cn 64
#define On 64
#define KP 200                // LDS A-row stride (shorts): 192 data + 8 pad
                              // KP*2=400 B: 16B-aligned rows, stride 100 dw ≡ 4 mod 32
#define OMP 66                // padded px stride for sOM

typedef __attribute__((ext_vector_type(8))) short bf16x8;
typedef __attribute__((ext_vector_type(4))) float f32x4;

// fp32 -> bf16 round-to-nearest-even
static __device__ __forceinline__ short f2bf(float f) {
    unsigned u = __builtin_bit_cast(unsigned, f);
    u += 0x7FFFu + ((u >> 16) & 1u);
    return (short)(u >> 16);
}

// workspace layout (in floats)
#define XT_OFF   0                            // NHWC x: B*H*W*C = 4,194,304
#define CONV_OFF (Bn*HW*Cn)                   // conv out: 4,194,304
#define PART_OFF (CONV_OFF + Bn*On*HW)        // 1024*128 partials
#define SS_OFF   (PART_OFF + 1024*128)        // 128
#define WT_OFF   (SS_OFF + 128)               // shorts: owT 288*64 + dwT 576*64

// ---------------------------------------------------------------------------
// Prep 1: NCHW -> NHWC fp32 transpose. Block = one (b,h) row, LDS-tiled.
// ---------------------------------------------------------------------------
__global__ __launch_bounds__(256) void nhwc_k(
    const float* __restrict__ x, float* __restrict__ xt)
{
    int bh = blockIdx.x;
    int b = bh >> 7, h = bh & 127;
    __shared__ float sT[64 * 133];     // [c][w], pad 133 (odd-ish stride)
    int t = threadIdx.x;
    const float* xp = x + (size_t)b * Cn * HW + (size_t)h * Ww;
#pragma unroll
    for (int it = 0; it < 32; ++it) {
        int idx = t + 256 * it;        // c(6b) | w(7b)
        int c = idx >> 7, w = idx & 127;
        sT[c * 133 + w] = xp[(size_t)c * HW + w];   // coalesced over w
    }
    __syncthreads();
    float* op = xt + ((size_t)bh * Ww) * 64;
#pragma unroll
    for (int it = 0; it < 32; ++it) {
        int idx = t + 256 * it;        // w(7b) | c(6b)
        int w = idx >> 6, c = idx & 63;
        op[(size_t)w * 64 + c] = sT[c * 133 + w];   // coalesced over c
    }
}

// ---------------------------------------------------------------------------
// Prep 2: pack weights bf16 tap-major [o][tap][c]. owT padded to o=32 (zeros).
// ---------------------------------------------------------------------------
__global__ __launch_bounds__(64) void wpack_k(
    const float* __restrict__ ow, const float* __restrict__ dw,
    short* __restrict__ owT, short* __restrict__ dwT)
{
    int u = blockIdx.x;               // 0..287: owT rows; 288..863: dwT rows
    int c = threadIdx.x;
    if (u < 288) {
        int o = u / 9, kk = u % 9;
        float v = (o < 27) ? ow[(size_t)o * 576 + c * 9 + kk] : 0.0f;
        owT[(size_t)u * 64 + c] = f2bf(v);
    } else {
        int u2 = u - 288;
        int o = u2 / 9, kk = u2 % 9;
        dwT[(size_t)u2 * 64 + c] = f2bf(dw[(size_t)o * 576 + c * 9 + kk]);
    }
}

// ---------------------------------------------------------------------------
// Fused: offset-conv GEMM -> bilinear prep -> deformable sampling -> DCN GEMM
// -> conv store + BN stats partials.  Block = half-row (64 px), grid 1024.
// K permuted tap-major: chunk ck = taps {3ck..3ck+2}, kc = kkl*64 + c.
// Fill units are WAVE-UNIFORM (px,tap); lanes = channels -> coalesced 256 B
// corner loads and contiguous 128 B LDS writes (2-way, free).
// CRITICAL #1: no __launch_bounds__ min-waves arg (R3 spill disaster).
// CRITICAL #2: wave id readfirstlane'd (R4 divergent-uniform trap).
// MFMA 16x16x32 bf16: A lane=[m=l15][k=quad*8+j]; B lane=[k=quad*8+j][n=l15];
// D lane=[row=quad*4+r][col=l15]  (validated in R8).
// ---------------------------------------------------------------------------
__global__ __launch_bounds__(256) void dcn_fused_k(
    const float* __restrict__ xt,  const short* __restrict__ owT,
    const float* __restrict__ ob,  const short* __restrict__ dwT,
    float* __restrict__ conv,      float* __restrict__ part)
{
    int blk  = blockIdx.x;          // b(2b) | h(7b) | half(1b)
    int half = blk & 1;
    int h    = (blk >> 1) & 127;
    int b    = blk >> 8;
    int px0  = half * 64;
    int t    = threadIdx.x;
    int lane = t & 63;
    int quad = lane >> 4;
    int l15  = lane & 15;
    int w_s  = __builtin_amdgcn_readfirstlane(t >> 6);   // 0..3 (SGPR)

    __shared__ short sA[64 * KP];       // 25,600 B  [px][kc]
    __shared__ float sOM[27 * OMP];     //  7,128 B  [o][px]

    const float* xb = xt + (size_t)b * HW * 64;

    // ================= Phase 1: offset conv GEMM =================
    int nt_o = w_s & 1;                 // n-tile (o 0..15 / 16..31)
    int mh   = w_s >> 1;                // m-half (px 0..31 / 32..63)
    int o_ow = nt_o * 16 + l15;
    f32x4 oacc[2] = {{0,0,0,0},{0,0,0,0}};

    for (int ck = 0; ck < 3; ++ck) {
        // ---- im2col fill: 192 units (kkl x px), wave-uniform, lanes = c
#pragma unroll 4
        for (int uu = 0; uu < 48; ++uu) {
            int unit = uu * 4 + w_s;
            int kkl = unit >> 6, px = unit & 63;
            int yy = h + ck - 1;
            int xx = px0 + px + kkl - 1;
            bool valid = ((unsigned)yy < (unsigned)Hh) && ((unsigned)xx < (unsigned)Ww);
            float v = valid ? xb[((size_t)yy * Ww + xx) * 64 + lane] : 0.0f;
            sA[px * KP + kkl * 64 + lane] = f2bf(v);
        }
        __syncthreads();
        // ---- GEMM: 6 ksteps, 2 m-tiles
#pragma unroll
        for (int ks = 0; ks < 6; ++ks) {
            int kk = ck * 3 + (ks >> 1);
            bf16x8 bfr = *(const bf16x8*)&owT[((size_t)o_ow * 9 + kk) * 64
                                             + (ks & 1) * 32 + quad * 8];
#pragma unroll
            for (int m2 = 0; m2 < 2; ++m2) {
                bf16x8 a = *(const bf16x8*)&sA[(mh * 32 + m2 * 16 + l15) * KP
                                               + ks * 32 + quad * 8];
                oacc[m2] = __builtin_amdgcn_mfma_f32_16x16x32_bf16(a, bfr, oacc[m2], 0, 0, 0);
            }
        }
        __syncthreads();
    }
    // ---- D -> sOM (+bias)
    if (o_ow < 27) {
        float bias = ob[o_ow];
#pragma unroll
        for (int m2 = 0; m2 < 2; ++m2) {
            int pxb = (mh * 2 + m2) * 16 + quad * 4;
#pragma unroll
            for (int r = 0; r < 4; ++r)
                sOM[o_ow * OMP + pxb + r] = oacc[m2][r] + bias;
        }
    }
    __syncthreads();

    // ================= Phase 2+3: sampling fill + DCN GEMM =================
    int o_dw = w_s * 16 + l15;
    f32x4 acc[4] = {{0,0,0,0},{0,0,0,0},{0,0,0,0},{0,0,0,0}};

    for (int ck = 0; ck < 3; ++ck) {
        // ---- sampling fill: unit wave-uniform, prep recomputed from sOM
#pragma unroll 2
        for (int uu = 0; uu < 48; ++uu) {
            int unit = uu * 4 + w_s;
            int kkl = unit >> 6, px = unit & 63;
            int kk = ck * 3 + kkl;          // tap: ky = ck, kx = kkl
            float ox = sOM[kk * OMP + px];
            float oy = sOM[(9 + kk) * OMP + px];
            float mr = sOM[(18 + kk) * OMP + px];
            float m  = 1.0f / (1.0f + __expf(-mr));
            float py  = (float)(h - 1 + ck) + oy;
            float pxf = (float)(px0 + px - 1 + kkl) + ox;
            float y0f = floorf(py), x0f = floorf(pxf);
            int y0 = (int)y0f, x0 = (int)x0f;
            float wy = py - y0f, wx = pxf - x0f;
            float v = 0.0f;
#pragma unroll
            for (int dy = 0; dy < 2; ++dy) {
#pragma unroll
                for (int dx = 0; dx < 2; ++dx) {
                    int yi = y0 + dy, xi = x0 + dx;
                    bool valid = (yi >= 0) && (yi < Hh) && (xi >= 0) && (xi < Ww);
                    int yc = min(max(yi, 0), Hh - 1);
                    int xc = min(max(xi, 0), Ww - 1);
                    float wgt = (dy ? wy : 1.0f - wy) * (dx ? wx : 1.0f - wx);
                    float cv = xb[((size_t)yc * Ww + xc) * 64 + lane];  // coalesced
                    v += (valid ? (wgt * m) : 0.0f) * cv;
                }
            }
            sA[px * KP + kkl * 64 + lane] = f2bf(v);
        }
        __syncthreads();
        // ---- GEMM: 6 ksteps, 4 m-tiles
#pragma unroll
        for (int ks = 0; ks < 6; ++ks) {
            int kk = ck * 3 + (ks >> 1);
            bf16x8 bfr = *(const bf16x8*)&dwT[((size_t)o_dw * 9 + kk) * 64
                                              + (ks & 1) * 32 + quad * 8];
#pragma unroll
            for (int mt = 0; mt < 4; ++mt) {
                bf16x8 a = *(const bf16x8*)&sA[(mt * 16 + l15) * KP
                                               + ks * 32 + quad * 8];
                acc[mt] = __builtin_amdgcn_mfma_f32_16x16x32_bf16(a, bfr, acc[mt], 0, 0, 0);
            }
        }
        __syncthreads();
    }

    // ================= Phase 4: store conv + stats partials =================
#pragma unroll
    for (int mt = 0; mt < 4; ++mt) {
        size_t idx = ((size_t)b * On + o_dw) * HW + (size_t)h * Ww + px0 + mt * 16 + quad * 4;
        *(f32x4*)(conv + idx) = acc[mt];
    }
    float s1 = 0.0f, s2 = 0.0f;
#pragma unroll
    for (int mt = 0; mt < 4; ++mt) {
#pragma unroll
        for (int r = 0; r < 4; ++r) {
            float v = acc[mt][r];
            s1 += v;
            s2 += v * v;
        }
    }
    s1 += __shfl_down(s1, 32, 64);  s2 += __shfl_down(s2, 32, 64);
    s1 += __shfl_down(s1, 16, 64);  s2 += __shfl_down(s2, 16, 64);
    if (lane < 16) {
        part[(size_t)blk * 128 + o_dw]      = s1;
        part[(size_t)blk * 128 + 64 + o_dw] = s2;
    }
}

// ---------------------------------------------------------------------------
// Stats reduce: 1024 partial rows -> BN scale/shift per channel.
// ---------------------------------------------------------------------------
__global__ __launch_bounds__(1024) void stats_k(
    const float* __restrict__ part, const float* __restrict__ gamma,
    const float* __restrict__ beta, float* __restrict__ ss)
{
    int t = threadIdx.x;
    int col = t & 127, grp = t >> 7;
    float a = 0.0f;
    for (int i = grp; i < Bn * Hh * 2; i += 8) a += part[(size_t)i * 128 + col];
    __shared__ float red[1024];
    red[t] = a;
    __syncthreads();
    if (t < 128) {
        float v = 0.0f;
#pragma unroll
        for (int k = 0; k < 8; ++k) v += red[t + 128 * k];
        red[t] = v;
    }
    __syncthreads();
    if (t < 64) {
        float n = (float)(Bn * HW);
        float mu = red[t] / n;
        float var = red[64 + t] / n - mu * mu;
        float sc = gamma[t] * rsqrtf(var + 1e-5f);
        ss[t] = sc;
        ss[64 + t] = beta[t] - mu * sc;
    }
}

// ---------------------------------------------------------------------------
// BN + ReLU apply, float4
// ---------------------------------------------------------------------------
__global__ __launch_bounds__(256) void bnrelu_k(
    const float* __restrict__ conv, const float* __restrict__ ss,
    float* __restrict__ out)
{
    int i = blockIdx.x * blockDim.x + threadIdx.x;
    int ch = (i >> 12) & 63;
    float sc = ss[ch];
    float sh = ss[64 + ch];
    const float4* cv = (const float4*)conv;
    float4* ov = (float4*)out;
    float4 v = cv[i];
    v.x = fmaxf(v.x * sc + sh, 0.0f);
    v.y = fmaxf(v.y * sc + sh, 0.0f);
    v.z = fmaxf(v.z * sc + sh, 0.0f);
    v.w = fmaxf(v.w * sc + sh, 0.0f);
    ov[i] = v;
}

// ---------------------------------------------------------------------------
extern "C" void kernel_launch(void* const* d_in, const int* in_sizes, int n_in,
                              void* d_out, int out_size, void* d_ws, size_t ws_size,
                              hipStream_t stream)
{
    const float* x     = (const float*)d_in[0];
    const float* ow    = (const float*)d_in[1];
    const float* ob    = (const float*)d_in[2];
    const float* dw    = (const float*)d_in[3];
    // d_in[4] = dcn_b: cancels exactly under BN mean subtraction -> unused
    const float* gamma = (const float*)d_in[5];
    const float* beta  = (const float*)d_in[6];

    float* ws   = (float*)d_ws;
    float* xt   = ws + XT_OFF;
    float* conv = ws + CONV_OFF;
    float* part = ws + PART_OFF;
    float* ss   = ws + SS_OFF;
    short* owT  = (short*)(ws + WT_OFF);
    short* dwT  = owT + 288 * 64;

    nhwc_k   <<<dim3(Bn * Hh),     dim3(256),  0, stream>>>(x, xt);
    wpack_k  <<<dim3(864),         dim3(64),   0, stream>>>(ow, dw, owT, dwT);
    dcn_fused_k<<<dim3(Bn * Hh * 2), dim3(256), 0, stream>>>(xt, owT, ob, dwT, conv, part);
    stats_k  <<<dim3(1),           dim3(1024), 0, stream>>>(part, gamma, beta, ss);
    bnrelu_k <<<dim3(Bn * On * HW / 4 / 256), dim3(256), 0, stream>>>(conv, ss, (float*)d_out);
}

// Round 10
// 170.598 us; speedup vs baseline: 3.6689x; 1.3857x over previous
//
#include <hip/hip_runtime.h>
#include <math.h>

#define Hh 128
#define Ww 128
#define HW (Hh*Ww)
#define Bn 4
#define Cn 64
#define On 64
#define KP 200                // LDS A-row stride (shorts): 192 data + 8 pad
#define OMP 66                // padded px stride for sOM (f16)

typedef __attribute__((ext_vector_type(8))) short bf16x8;
typedef __attribute__((ext_vector_type(4))) float f32x4;

// fp32 -> bf16 round-to-nearest-even
static __device__ __forceinline__ short f2bf(float f) {
    unsigned u = __builtin_bit_cast(unsigned, f);
    u += 0x7FFFu + ((u >> 16) & 1u);
    return (short)(u >> 16);
}
static __device__ __forceinline__ short f2h(float f) {
    _Float16 h = (_Float16)f;
    return __builtin_bit_cast(short, h);
}
static __device__ __forceinline__ float h2f(short s) {
    return (float)__builtin_bit_cast(_Float16, s);
}

// workspace layout (in floats)
#define XT_OFF   0                            // NHWC x: B*H*W*C = 4,194,304
#define CONV_OFF (Bn*HW*Cn)                   // conv out: 4,194,304
#define PART_OFF (CONV_OFF + Bn*On*HW)        // 1024*128 partials
#define SS_OFF   (PART_OFF + 1024*128)        // 128
#define WT_OFF   (SS_OFF + 128)               // shorts: owT 288*64 + dwT 576*64

// ---------------------------------------------------------------------------
// Prep 1: NCHW -> NHWC fp32 transpose. Block = one (b,h) row, LDS-tiled.
// ---------------------------------------------------------------------------
__global__ __launch_bounds__(256) void nhwc_k(
    const float* __restrict__ x, float* __restrict__ xt)
{
    int bh = blockIdx.x;
    int b = bh >> 7, h = bh & 127;
    __shared__ float sT[64 * 133];
    int t = threadIdx.x;
    const float* xp = x + (size_t)b * Cn * HW + (size_t)h * Ww;
#pragma unroll
    for (int it = 0; it < 32; ++it) {
        int idx = t + 256 * it;        // c(6b) | w(7b)
        int c = idx >> 7, w = idx & 127;
        sT[c * 133 + w] = xp[(size_t)c * HW + w];
    }
    __syncthreads();
    float* op = xt + ((size_t)bh * Ww) * 64;
#pragma unroll
    for (int it = 0; it < 32; ++it) {
        int idx = t + 256 * it;        // w(7b) | c(6b)
        int w = idx >> 6, c = idx & 63;
        op[(size_t)w * 64 + c] = sT[c * 133 + w];
    }
}

// ---------------------------------------------------------------------------
// Prep 2: pack weights bf16 tap-major [o][tap][c]. owT padded to o=32.
// ---------------------------------------------------------------------------
__global__ __launch_bounds__(64) void wpack_k(
    const float* __restrict__ ow, const float* __restrict__ dw,
    short* __restrict__ owT, short* __restrict__ dwT)
{
    int u = blockIdx.x;
    int c = threadIdx.x;
    if (u < 288) {
        int o = u / 9, kk = u % 9;
        float v = (o < 27) ? ow[(size_t)o * 576 + c * 9 + kk] : 0.0f;
        owT[(size_t)u * 64 + c] = f2bf(v);
    } else {
        int u2 = u - 288;
        int o = u2 / 9, kk = u2 % 9;
        dwT[(size_t)u2 * 64 + c] = f2bf(dw[(size_t)o * 576 + c * 9 + kk]);
    }
}

// ---------------------------------------------------------------------------
// Fused: offset-conv GEMM -> per-thread bilinear prep (to LDS) -> coalesced
// sampling fill -> DCN GEMM -> conv store + BN stats partials.
// Block = half-row (64 px), grid 1024, XCD-swizzled.
// Prep is computed ONCE per unit by its owning thread (R9 recomputed the
// ~50-op prep per unit per wave = 64x VALU inflation, VALUBusy 61%).
// CRITICAL #1: no __launch_bounds__ min-waves arg (R3 spill disaster).
// CRITICAL #2: wave id readfirstlane'd (R4 divergent-uniform trap).
// MFMA 16x16x32 bf16: A lane=[m=l15][k=quad*8+j]; B lane=[k=quad*8+j][n=l15];
// D lane=[row=quad*4+r][col=l15]  (validated R8/R9).
// LDS: sA 25600 + sOMh 3584 + prepIdx 4608 + prepW 4608 = 38400 B -> 4 blk/CU.
// ---------------------------------------------------------------------------
__global__ __launch_bounds__(256) void dcn_fused_k(
    const float* __restrict__ xt,  const short* __restrict__ owT,
    const float* __restrict__ ob,  const short* __restrict__ dwT,
    float* __restrict__ conv,      float* __restrict__ part)
{
    // XCD swizzle: consecutive raw ids round-robin XCDs; give each XCD a
    // contiguous (b, h-slab) so its ~2 MB slab fits the 4 MB per-XCD L2.
    int raw  = blockIdx.x;
    int blk  = ((raw & 7) << 7) | (raw >> 3);   // b(2b) | h(7b) | half(1b)
    int half = blk & 1;
    int h    = (blk >> 1) & 127;
    int b    = blk >> 8;
    int px0  = half * 64;
    int t    = threadIdx.x;
    int lane = t & 63;
    int quad = lane >> 4;
    int l15  = lane & 15;
    int w_s  = __builtin_amdgcn_readfirstlane(t >> 6);   // 0..3 (SGPR)

    __shared__ __align__(16) short sA[64 * KP];     // 25600 B  [px][kc] bf16
    __shared__ __align__(16) short sOMh[27 * OMP + 10]; // 3584 B [o][px] f16
    __shared__ __align__(16) unsigned short prepIdx[576 * 4]; // 4608 B
    __shared__ __align__(16) short prepW[576 * 4];            // 4608 B

    const float* xb = xt + (size_t)b * HW * 64;

    // ================= Phase 1: offset conv GEMM =================
    int nt_o = w_s & 1;
    int mh   = w_s >> 1;
    int o_ow = nt_o * 16 + l15;
    f32x4 oacc[2] = {{0,0,0,0},{0,0,0,0}};

    for (int ck = 0; ck < 3; ++ck) {
        // ---- im2col fill: 192 units (kkl x px), wave-uniform, lanes = c
#pragma unroll 4
        for (int uu = 0; uu < 48; ++uu) {
            int unit = uu * 4 + w_s;
            int kkl = unit >> 6, px = unit & 63;
            int yy = h + ck - 1;
            int xx = px0 + px + kkl - 1;
            bool valid = ((unsigned)yy < (unsigned)Hh) && ((unsigned)xx < (unsigned)Ww);
            float v = valid ? xb[((size_t)yy * Ww + xx) * 64 + lane] : 0.0f;
            sA[px * KP + kkl * 64 + lane] = f2bf(v);
        }
        __syncthreads();
#pragma unroll
        for (int ks = 0; ks < 6; ++ks) {
            int kk = ck * 3 + (ks >> 1);
            bf16x8 bfr = *(const bf16x8*)&owT[((size_t)o_ow * 9 + kk) * 64
                                             + (ks & 1) * 32 + quad * 8];
#pragma unroll
            for (int m2 = 0; m2 < 2; ++m2) {
                bf16x8 a = *(const bf16x8*)&sA[(mh * 32 + m2 * 16 + l15) * KP
                                               + ks * 32 + quad * 8];
                oacc[m2] = __builtin_amdgcn_mfma_f32_16x16x32_bf16(a, bfr, oacc[m2], 0, 0, 0);
            }
        }
        __syncthreads();
    }
    // ---- D -> sOMh (+bias), f16
    if (o_ow < 27) {
        float bias = ob[o_ow];
#pragma unroll
        for (int m2 = 0; m2 < 2; ++m2) {
            int pxb = (mh * 2 + m2) * 16 + quad * 4;
#pragma unroll
            for (int r = 0; r < 4; ++r)
                sOMh[o_ow * OMP + pxb + r] = f2h(oacc[m2][r] + bias);
        }
    }
    __syncthreads();

    // ================= Phase 2: per-thread bilinear prep -> LDS ==========
    // 576 units = tap(9) x px(64); thread owns u = t, t+256, t+512(<576)
#pragma unroll
    for (int i = 0; i < 3; ++i) {
        int u = t + 256 * i;
        if (u < 576) {
            int kk = u >> 6, px = u & 63;
            float ox = h2f(sOMh[kk * OMP + px]);
            float oy = h2f(sOMh[(9 + kk) * OMP + px]);
            float mr = h2f(sOMh[(18 + kk) * OMP + px]);
            float m  = 1.0f / (1.0f + __expf(-mr));
            float py  = (float)(h - 1 + (kk / 3)) + oy;
            float pxf = (float)(px0 + px - 1 + (kk % 3)) + ox;
            float y0f = floorf(py), x0f = floorf(pxf);
            int y0 = (int)y0f, x0 = (int)x0f;
            float wy = py - y0f, wx = pxf - x0f;
#pragma unroll
            for (int dy = 0; dy < 2; ++dy) {
#pragma unroll
                for (int dx = 0; dx < 2; ++dx) {
                    int yi = y0 + dy, xi = x0 + dx;
                    bool valid = (yi >= 0) && (yi < Hh) && (xi >= 0) && (xi < Ww);
                    int yc = min(max(yi, 0), Hh - 1);
                    int xc = min(max(xi, 0), Ww - 1);
                    float wgt = (dy ? wy : 1.0f - wy) * (dx ? wx : 1.0f - wx);
                    prepIdx[u * 4 + dy * 2 + dx] = (unsigned short)(yc * Ww + xc);
                    prepW[u * 4 + dy * 2 + dx]   = f2h(valid ? (wgt * m) : 0.0f);
                }
            }
        }
    }
    __syncthreads();

    // ================= Phase 3: sampling fill + DCN GEMM =================
    int o_dw = w_s * 16 + l15;
    f32x4 acc[4] = {{0,0,0,0},{0,0,0,0},{0,0,0,0},{0,0,0,0}};

    for (int ck = 0; ck < 3; ++ck) {
#pragma unroll 4
        for (int uu = 0; uu < 48; ++uu) {
            int unit = uu * 4 + w_s;             // wave-uniform
            int kkl = unit >> 6, px = unit & 63;
            int u = ck * 192 + unit;             // global unit = kk*64+px
            // broadcast prep (uniform address ds_read, conflict-free)
            const unsigned short* pi = &prepIdx[u * 4];
            const short*          pw = &prepW[u * 4];
            float v = 0.0f;
#pragma unroll
            for (int j = 0; j < 4; ++j) {
                float cv = xb[(size_t)pi[j] * 64 + lane];   // coalesced 256 B
                v += h2f(pw[j]) * cv;
            }
            sA[px * KP + kkl * 64 + lane] = f2bf(v);
        }
        __syncthreads();
#pragma unroll
        for (int ks = 0; ks < 6; ++ks) {
            int kk = ck * 3 + (ks >> 1);
            bf16x8 bfr = *(const bf16x8*)&dwT[((size_t)o_dw * 9 + kk) * 64
                                              + (ks & 1) * 32 + quad * 8];
#pragma unroll
            for (int mt = 0; mt < 4; ++mt) {
                bf16x8 a = *(const bf16x8*)&sA[(mt * 16 + l15) * KP
                                               + ks * 32 + quad * 8];
                acc[mt] = __builtin_amdgcn_mfma_f32_16x16x32_bf16(a, bfr, acc[mt], 0, 0, 0);
            }
        }
        __syncthreads();
    }

    // ================= Phase 4: store conv + stats partials =================
#pragma unroll
    for (int mt = 0; mt < 4; ++mt) {
        size_t idx = ((size_t)b * On + o_dw) * HW + (size_t)h * Ww + px0 + mt * 16 + quad * 4;
        *(f32x4*)(conv + idx) = acc[mt];
    }
    float s1 = 0.0f, s2 = 0.0f;
#pragma unroll
    for (int mt = 0; mt < 4; ++mt) {
#pragma unroll
        for (int r = 0; r < 4; ++r) {
            float v = acc[mt][r];
            s1 += v;
            s2 += v * v;
        }
    }
    s1 += __shfl_down(s1, 32, 64);  s2 += __shfl_down(s2, 32, 64);
    s1 += __shfl_down(s1, 16, 64);  s2 += __shfl_down(s2, 16, 64);
    if (lane < 16) {
        part[(size_t)blk * 128 + o_dw]      = s1;
        part[(size_t)blk * 128 + 64 + o_dw] = s2;
    }
}

// ---------------------------------------------------------------------------
// Stats reduce: 1024 partial rows -> BN scale/shift per channel.
// 4 independent accumulators to break the dependent-add latency chain.
// ---------------------------------------------------------------------------
__global__ __launch_bounds__(1024) void stats_k(
    const float* __restrict__ part, const float* __restrict__ gamma,
    const float* __restrict__ beta, float* __restrict__ ss)
{
    int t = threadIdx.x;
    int col = t & 127, grp = t >> 7;
    float a0 = 0.0f, a1 = 0.0f, a2 = 0.0f, a3 = 0.0f;
    for (int i = grp; i < Bn * Hh * 2; i += 32) {
        a0 += part[(size_t)i * 128 + col];
        a1 += part[(size_t)(i + 8)  * 128 + col];
        a2 += part[(size_t)(i + 16) * 128 + col];
        a3 += part[(size_t)(i + 24) * 128 + col];
    }
    __shared__ float red[1024];
    red[t] = (a0 + a1) + (a2 + a3);
    __syncthreads();
    if (t < 128) {
        float v = 0.0f;
#pragma unroll
        for (int k = 0; k < 8; ++k) v += red[t + 128 * k];
        red[t] = v;
    }
    __syncthreads();
    if (t < 64) {
        float n = (float)(Bn * HW);
        float mu = red[t] / n;
        float var = red[64 + t] / n - mu * mu;
        float sc = gamma[t] * rsqrtf(var + 1e-5f);
        ss[t] = sc;
        ss[64 + t] = beta[t] - mu * sc;
    }
}

// ---------------------------------------------------------------------------
// BN + ReLU apply, float4
// ---------------------------------------------------------------------------
__global__ __launch_bounds__(256) void bnrelu_k(
    const float* __restrict__ conv, const float* __restrict__ ss,
    float* __restrict__ out)
{
    int i = blockIdx.x * blockDim.x + threadIdx.x;
    int ch = (i >> 12) & 63;
    float sc = ss[ch];
    float sh = ss[64 + ch];
    const float4* cv = (const float4*)conv;
    float4* ov = (float4*)out;
    float4 v = cv[i];
    v.x = fmaxf(v.x * sc + sh, 0.0f);
    v.y = fmaxf(v.y * sc + sh, 0.0f);
    v.z = fmaxf(v.z * sc + sh, 0.0f);
    v.w = fmaxf(v.w * sc + sh, 0.0f);
    ov[i] = v;
}

// ---------------------------------------------------------------------------
extern "C" void kernel_launch(void* const* d_in, const int* in_sizes, int n_in,
                              void* d_out, int out_size, void* d_ws, size_t ws_size,
                              hipStream_t stream)
{
    const float* x     = (const float*)d_in[0];
    const float* ow    = (const float*)d_in[1];
    const float* ob    = (const float*)d_in[2];
    const float* dw    = (const float*)d_in[3];
    // d_in[4] = dcn_b: cancels exactly under BN mean subtraction -> unused
    const float* gamma = (const float*)d_in[5];
    const float* beta  = (const float*)d_in[6];

    float* ws   = (float*)d_ws;
    float* xt   = ws + XT_OFF;
    float* conv = ws + CONV_OFF;
    float* part = ws + PART_OFF;
    float* ss   = ws + SS_OFF;
    short* owT  = (short*)(ws + WT_OFF);
    short* dwT  = owT + 288 * 64;

    nhwc_k   <<<dim3(Bn * Hh),       dim3(256),  0, stream>>>(x, xt);
    wpack_k  <<<dim3(864),           dim3(64),   0, stream>>>(ow, dw, owT, dwT);
    dcn_fused_k<<<dim3(Bn * Hh * 2), dim3(256),  0, stream>>>(xt, owT, ob, dwT, conv, part);
    stats_k  <<<dim3(1),             dim3(1024), 0, stream>>>(part, gamma, beta, ss);
    bnrelu_k <<<dim3(Bn * On * HW / 4 / 256), dim3(256), 0, stream>>>(conv, ss, (float*)d_out);
}